// Round 13
// baseline (192.460 us; speedup 1.0000x reference)
//
#include <hip/hip_runtime.h>
#include <hip/hip_bf16.h>

typedef unsigned short u16;
typedef __bf16 bf16x8 __attribute__((ext_vector_type(8)));
typedef float  f32x4  __attribute__((ext_vector_type(4)));

#define BB    4
#define SS    4096
#define DD    1024
#define EE    8
#define M_TOT (BB*SS)   /* 16384 */
#define N_TOT DD        /* 1024  */
#define K_TOT DD        /* 1024  */

#define BM 256
#define BN 128
#define BK 64
#define NT (K_TOT/BK)   /* 16 K-tiles */

#define GATE_BLOCKS 1024   /* 16 tokens per block, 4 per wave */

__device__ __forceinline__ u16 f2bf(float f) {
  unsigned u = __builtin_bit_cast(unsigned, f);
  u += 0x7fffu + ((u >> 16) & 1u);          // round-to-nearest-even
  return (u16)(u >> 16);
}

__device__ __forceinline__ void stage16(u16* lds, const u16* g) {
  __builtin_amdgcn_global_load_lds((const __attribute__((address_space(1))) void*)g,
                                   (__attribute__((address_space(3))) void*)lds,
                                   16, 0, 0);
}

// ---------------------------------------------------------------------------
// Kernel 1: gate (fp32, exact) + token f32->bf16 convert, plus weight convert.
// (unchanged — measured ~92% of achievable HBM BW)
// ---------------------------------------------------------------------------
__global__ __launch_bounds__(256) void gate_convert_kernel(
    const float* __restrict__ tokens, const float* __restrict__ gate_w,
    const float* __restrict__ w0,     const float* __restrict__ w1,
    u16* __restrict__ tok_bf, u16* __restrict__ w0_bf, u16* __restrict__ w1_bf,
    float* __restrict__ scales)
{
  const int bid = blockIdx.x;
  const int tid = threadIdx.x;

  if (bid < GATE_BLOCKS) {
    __shared__ float gwT[EE][DD];       // 32 KB, transposed gate weights
    #pragma unroll
    for (int r = 0; r < 4; ++r) {
      const int d = r * 256 + tid;      // coalesced: lanes 32B apart
      float4 a = *(const float4*)&gate_w[d * EE];
      float4 b = *(const float4*)&gate_w[d * EE + 4];
      gwT[0][d] = a.x; gwT[1][d] = a.y; gwT[2][d] = a.z; gwT[3][d] = a.w;
      gwT[4][d] = b.x; gwT[5][d] = b.y; gwT[6][d] = b.z; gwT[7][d] = b.w;
    }
    __syncthreads();

    const int lane = tid & 63, wid = tid >> 6;
    const int tbase = (bid * 4 + wid) * 4;          // 4 tokens per wave

    float lg[4][EE];
    #pragma unroll
    for (int t = 0; t < 4; ++t)
      #pragma unroll
      for (int e = 0; e < EE; ++e) lg[t][e] = 0.0f;

    #pragma unroll
    for (int c = 0; c < 4; ++c) {
      const int d = c * 256 + lane * 4;
      float4 gw[EE];
      #pragma unroll
      for (int e = 0; e < EE; ++e)
        gw[e] = *(const float4*)&gwT[e][d];         // ds_read_b128, lanes 16B apart
      #pragma unroll
      for (int t = 0; t < 4; ++t) {
        const size_t off = (size_t)(tbase + t) * DD + d;
        float4 v = *(const float4*)(tokens + off);
        *(ushort4*)(tok_bf + off) =
            make_ushort4(f2bf(v.x), f2bf(v.y), f2bf(v.z), f2bf(v.w));
        #pragma unroll
        for (int e = 0; e < EE; ++e)
          lg[t][e] = fmaf(v.w, gw[e].w, fmaf(v.z, gw[e].z,
                     fmaf(v.y, gw[e].y, fmaf(v.x, gw[e].x, lg[t][e]))));
      }
    }

    // Expert-splitting butterfly reduce, then shuffle softmax/top-2.
    const int b0 = lane & 1, b1 = (lane >> 1) & 1, b2 = (lane >> 2) & 1;
    const int E  = b0 * 4 + (lane & 2) + b2;

    #pragma unroll
    for (int t = 0; t < 4; ++t) {
      float n0[4], n1[2], rr;
      #pragma unroll
      for (int i = 0; i < 4; ++i) {
        float send = b0 ? lg[t][i] : lg[t][i + 4];
        float keep = b0 ? lg[t][i + 4] : lg[t][i];
        n0[i] = keep + __shfl_xor(send, 1, 64);
      }
      #pragma unroll
      for (int i = 0; i < 2; ++i) {
        float send = b1 ? n0[i] : n0[i + 2];
        float keep = b1 ? n0[i + 2] : n0[i];
        n1[i] = keep + __shfl_xor(send, 2, 64);
      }
      {
        float send = b2 ? n1[0] : n1[1];
        float keep = b2 ? n1[1] : n1[0];
        rr = keep + __shfl_xor(send, 4, 64);
      }
      rr += __shfl_xor(rr, 8, 64);
      rr += __shfl_xor(rr, 16, 64);
      rr += __shfl_xor(rr, 32, 64);

      float m = rr;
      m = fmaxf(m, __shfl_xor(m, 1, 64));
      m = fmaxf(m, __shfl_xor(m, 2, 64));
      m = fmaxf(m, __shfl_xor(m, 4, 64));
      float p = __expf(rr - m);
      float s = p;
      s += __shfl_xor(s, 1, 64);
      s += __shfl_xor(s, 2, 64);
      s += __shfl_xor(s, 4, 64);

      int cnt = 0;
      #pragma unroll
      for (int k = 1; k < 8; ++k) {
        float Lo = __shfl_xor(rr, k, 64);
        const int Eo = E ^ ((k & 1) * 4 + (k & 2) + ((k >> 2) & 1));
        cnt += (Lo > rr || (Lo == rr && Eo < E)) ? 1 : 0;
      }
      if (lane < 8) {
        const float w = p / s;
        if (E == 0) scales[(tbase + t) * 2 + 0] = (cnt == 0) ? w : 0.0f;
        if (E == 1) scales[(tbase + t) * 2 + 1] = (cnt == 1) ? w : 0.0f;
      }
    }
  } else {
    const int wb = bid - GATE_BLOCKS;            // 0..2047
    const float* src = (wb < 1024) ? w0 : w1;
    u16*        dst = (wb < 1024) ? w0_bf : w1_bf;
    const int base = (wb & 1023) * 1024 + tid * 4;
    float4 v = *(const float4*)(src + base);
    *(ushort4*)(dst + base) =
        make_ushort4(f2bf(v.x), f2bf(v.y), f2bf(v.z), f2bf(v.w));
  }
}

// ---------------------------------------------------------------------------
// Kernel 2: fused dual-GEMM, v8: B operands DIRECT FROM GLOBAL (L2-resident
// weights), A via LDS.  Rationale (r12 audit): LDS pipe 2304 cyc/tile ~=
// MFMA 2483 cyc/tile -> even perfect overlap caps at ~50% MfmaUtil.  Moving
// B (128 KB/tile/CU) to the VMEM/L2 path drops LDS to ~1030 cyc/tile and
// makes MFMA the sole dominant pipe.  w0+w1 bf16 = 4 MB = one XCD L2; every
// block reads all of B -> permanently L2-hot.  B gather pattern: 16 rows
// 2 KB apart x 64 B contiguous = 16 full cache lines per wave-load, 100%
// utilization; 4 waves share wn -> 3/4 L1 hits.
// LDS: A-only double-buffer (64 KB).  One barrier + one manual vmcnt(0)
// per tile; all B waits are compiler-counted register deps.
// ---------------------------------------------------------------------------
__global__ __launch_bounds__(512, 2) void moe_gemm_kernel(
    const u16* __restrict__ A,    // [M,K] bf16
    const u16* __restrict__ Bw0,  // [N,K] bf16 (w0 row-major = B^T)
    const u16* __restrict__ Bw1,  // [N,K] bf16
    const float* __restrict__ bias0, const float* __restrict__ bias1,
    const float* __restrict__ scales, // [M,2]
    float* __restrict__ out)      // [M,N] f32
{
  __shared__ u16 lA[2][BM * BK];    // 64 KiB total

  const int tid = threadIdx.x;

  // bijective XCD swizzle: 512 blocks, 8 XCDs, 64 blocks/XCD chunk.
  const int wgid = (blockIdx.x & 7) * 64 + (blockIdx.x >> 3);
  const int bm = wgid >> 3, bn = wgid & 7;    // bn fastest: XCD shares A panels
  const int m0 = bm * BM, n0 = bn * BN;

  const int lane = tid & 63;
  const int wid  = tid >> 6;                  // 0..7
  const int wm = wid >> 1, wn = wid & 1;      // 4M x 2N wave grid
  const int fr = lane & 15, fq = lane >> 4;
  const int frh = fr >> 1;                    // A read-swizzle term

  // A staging (unchanged): row tid>>3, inverse-swizzled source chunk.
  const int schunk = ((tid & 7) ^ ((tid >> 4) & 7)) * 8;
  const u16* gA = A + (size_t)(m0 + (tid >> 3)) * K_TOT + schunk;

  // B: per-lane row bases for the 4 j-fragments (row = n0+wn*64+j*16+fr),
  // element offset fq*8 within the row; +kk*32 per k-half, +k0 per tile.
  const u16* gB0r[4];
  const u16* gB1r[4];
  #pragma unroll
  for (int j = 0; j < 4; ++j) {
    const int row = n0 + wn * 64 + j * 16 + fr;
    gB0r[j] = Bw0 + (size_t)row * K_TOT + fq * 8;
    gB1r[j] = Bw1 + (size_t)row * K_TOT + fq * 8;
  }

#define STAGE_A(buf, c, ko)  stage16(&lA[buf][(c)*4096 + tid*8], gA + (size_t)(c)*64*K_TOT + (ko))

#define FRAGA(buf, rowbase, kk) \
  (*(const bf16x8*)&lA[buf][((rowbase) + fr) * BK + ((((kk) << 2) | fq) ^ frh) * 8])

#define LOADB(P, kk, ko) (*(const bf16x8*)((P) + (ko) + (kk) * 32))

#define BAR()        __builtin_amdgcn_s_barrier()
#define WAIT_VM(N)   asm volatile("s_waitcnt vmcnt(" #N ")" ::: "memory")

#define MFMA16(ACC, AF, BF) do {                                              \
    __builtin_amdgcn_s_setprio(1);                                            \
    _Pragma("unroll")                                                         \
    for (int i = 0; i < 4; ++i)                                               \
      _Pragma("unroll")                                                       \
      for (int j = 0; j < 4; ++j)                                             \
        ACC[i][j] = __builtin_amdgcn_mfma_f32_16x16x32_bf16(AF[i], BF[j],     \
                                                            ACC[i][j], 0,0,0);\
    __builtin_amdgcn_s_setprio(0);                                            \
  } while (0)

  f32x4 acc0[4][4] = {};
  f32x4 acc1[4][4] = {};
  bf16x8 afA[4], afB[4], b0A[4], b0B[4], b1A[4], b1B[4];  // named banks

  // Prologue: stage A K-tile 0, drain, barrier.
  STAGE_A(0, 0, 0); STAGE_A(0, 1, 0); STAGE_A(0, 2, 0); STAGE_A(0, 3, 0);
  WAIT_VM(0);
  BAR();

  int cur = 0;
  // Steady tiles 0..NT-2 (each prefetches A tile t+1).
  for (int t = 0; t < NT - 1; ++t) {
    const int nxt = cur ^ 1;
    const size_t koN = (size_t)(t + 1) * BK;
    const int ko = t * BK;

    // A fragment reads (LDS, 8 x b128, counted lgkm by compiler)
    #pragma unroll
    for (int i = 0; i < 4; ++i) afA[i] = FRAGA(cur, wm * 64 + i * 16, 0);
    #pragma unroll
    for (int i = 0; i < 4; ++i) afB[i] = FRAGA(cur, wm * 64 + i * 16, 1);

    // B loads (global->VGPR, L2-hot; FIFO: b0A,b0B,b1A,b1B, then A' stage)
    #pragma unroll
    for (int j = 0; j < 4; ++j) b0A[j] = LOADB(gB0r[j], 0, ko);
    #pragma unroll
    for (int j = 0; j < 4; ++j) b0B[j] = LOADB(gB0r[j], 1, ko);
    #pragma unroll
    for (int j = 0; j < 4; ++j) b1A[j] = LOADB(gB1r[j], 0, ko);
    #pragma unroll
    for (int j = 0; j < 4; ++j) b1B[j] = LOADB(gB1r[j], 1, ko);
    STAGE_A(nxt, 0, koN); STAGE_A(nxt, 1, koN); STAGE_A(nxt, 2, koN); STAGE_A(nxt, 3, koN);

    MFMA16(acc0, afA, b0A);   // compiler: lgkm for afA, vmcnt(12) for b0A
    MFMA16(acc0, afB, b0B);   // vmcnt(8)
    MFMA16(acc1, afA, b1A);   // vmcnt(4) -- A' stages stay in flight
    MFMA16(acc1, afB, b1B);

    WAIT_VM(0);               // A' staged (issued ~3 batches ago: free)
    BAR();
    cur = nxt;
  }

  // Peeled last tile (no A prefetch).
  {
    const int ko = (NT - 1) * BK;
    #pragma unroll
    for (int i = 0; i < 4; ++i) afA[i] = FRAGA(cur, wm * 64 + i * 16, 0);
    #pragma unroll
    for (int i = 0; i < 4; ++i) afB[i] = FRAGA(cur, wm * 64 + i * 16, 1);
    #pragma unroll
    for (int j = 0; j < 4; ++j) b0A[j] = LOADB(gB0r[j], 0, ko);
    #pragma unroll
    for (int j = 0; j < 4; ++j) b0B[j] = LOADB(gB0r[j], 1, ko);
    #pragma unroll
    for (int j = 0; j < 4; ++j) b1A[j] = LOADB(gB1r[j], 0, ko);
    #pragma unroll
    for (int j = 0; j < 4; ++j) b1B[j] = LOADB(gB1r[j], 1, ko);
    MFMA16(acc0, afA, b0A);
    MFMA16(acc0, afB, b0B);
    MFMA16(acc1, afA, b1A);
    MFMA16(acc1, afB, b1B);
  }

  // Epilogue: out = s0*silu(acc0+b0) + s1*silu(acc1+b1)
  float bb0[4], bb1[4];
  #pragma unroll
  for (int j = 0; j < 4; ++j) {
    const int col = n0 + wn * 64 + j * 16 + fr;
    bb0[j] = bias0[col];
    bb1[j] = bias1[col];
  }
  #pragma unroll
  for (int i = 0; i < 4; ++i) {
    #pragma unroll
    for (int r = 0; r < 4; ++r) {
      const int grow = m0 + wm * 64 + i * 16 + fq * 4 + r;  // C row=(lane>>4)*4+reg
      const float s0 = scales[grow * 2 + 0];
      const float s1 = scales[grow * 2 + 1];
      float* orow = out + (size_t)grow * N_TOT + n0 + wn * 64;
      #pragma unroll
      for (int j = 0; j < 4; ++j) {
        const float v0 = acc0[i][j][r] + bb0[j];
        const float v1 = acc1[i][j][r] + bb1[j];
        const float g0 = v0 / (1.0f + __expf(-v0));
        const float g1 = v1 / (1.0f + __expf(-v1));
        orow[j * 16 + fr] = s0 * g0 + s1 * g1;              // col = lane&15
      }
    }
  }
#undef STAGE_A
#undef FRAGA
#undef LOADB
#undef BAR
#undef WAIT_VM
#undef MFMA16
}

// ---------------------------------------------------------------------------
extern "C" void kernel_launch(void* const* d_in, const int* in_sizes, int n_in,
                              void* d_out, int out_size, void* d_ws, size_t ws_size,
                              hipStream_t stream)
{
  const float* tokens = (const float*)d_in[0];
  const float* gate_w = (const float*)d_in[1];
  const float* w0     = (const float*)d_in[2];
  const float* b0     = (const float*)d_in[3];
  const float* w1     = (const float*)d_in[4];
  const float* b1     = (const float*)d_in[5];
  float* out = (float*)d_out;

  char* ws = (char*)d_ws;
  u16* tok_bf = (u16*)ws;                                               // 32 MB
  u16* w0_bf  = (u16*)(ws + (size_t)M_TOT * K_TOT * 2);                 //  2 MB
  u16* w1_bf  = (u16*)(ws + (size_t)M_TOT * K_TOT * 2 + (size_t)N_TOT * K_TOT * 2);
  float* scales = (float*)(ws + (size_t)M_TOT * K_TOT * 2 + (size_t)2 * N_TOT * K_TOT * 2);

  gate_convert_kernel<<<GATE_BLOCKS + 2048, 256, 0, stream>>>(
      tokens, gate_w, w0, w1, tok_bf, w0_bf, w1_bf, scales);

  moe_gemm_kernel<<<(M_TOT/BM) * (N_TOT/BN), 512, 0, stream>>>(
      tok_bf, w0_bf, w1_bf, b0, b1, scales, out);
}

// Round 14
// 95.402 us; speedup vs baseline: 2.0174x; 2.0174x over previous
//
#include <hip/hip_runtime.h>
#include <hip/hip_bf16.h>

typedef unsigned short u16;
typedef __bf16 bf16x8 __attribute__((ext_vector_type(8)));
typedef float  f32x4  __attribute__((ext_vector_type(4)));

#define BB    4
#define SS    4096
#define DD    1024
#define EE    8
#define M_TOT (BB*SS)   /* 16384 */
#define N_TOT DD        /* 1024  */
#define K_TOT DD        /* 1024  */

#define BK 64
#define NT (K_TOT/BK)   /* 16 K-tiles */

#define GATE_BLOCKS 1024   /* 16 tokens per block, 4 per wave */

__device__ __forceinline__ u16 f2bf(float f) {
  unsigned u = __builtin_bit_cast(unsigned, f);
  u += 0x7fffu + ((u >> 16) & 1u);          // round-to-nearest-even
  return (u16)(u >> 16);
}

__device__ __forceinline__ void stage16(u16* lds, const u16* g) {
  __builtin_amdgcn_global_load_lds((const __attribute__((address_space(1))) void*)g,
                                   (__attribute__((address_space(3))) void*)lds,
                                   16, 0, 0);
}

// ---------------------------------------------------------------------------
// Kernel 1: gate (fp32, exact) + token f32->bf16 convert + weight convert +
// ACTIVE-LIST build.  A token is active iff s0!=0 (top1==0) or s1!=0
// (top2==1) — the exact conditions whose scales are written.  Inactive rows
// (~77%) have output EXACTLY zero -> written here; active tokens appended to
// a compact list (atomicAdd; order nondeterministic but每 row written by one
// block later -> output invariant).
// ---------------------------------------------------------------------------
__global__ __launch_bounds__(256) void gate_convert_kernel(
    const float* __restrict__ tokens, const float* __restrict__ gate_w,
    const float* __restrict__ w0,     const float* __restrict__ w1,
    u16* __restrict__ tok_bf, u16* __restrict__ w0_bf, u16* __restrict__ w1_bf,
    float* __restrict__ scales, int* __restrict__ counter,
    int* __restrict__ list, float* __restrict__ outp)
{
  const int bid = blockIdx.x;
  const int tid = threadIdx.x;

  if (bid < GATE_BLOCKS) {
    __shared__ float gwT[EE][DD];       // 32 KB, transposed gate weights
    #pragma unroll
    for (int r = 0; r < 4; ++r) {
      const int d = r * 256 + tid;      // coalesced: lanes 32B apart
      float4 a = *(const float4*)&gate_w[d * EE];
      float4 b = *(const float4*)&gate_w[d * EE + 4];
      gwT[0][d] = a.x; gwT[1][d] = a.y; gwT[2][d] = a.z; gwT[3][d] = a.w;
      gwT[4][d] = b.x; gwT[5][d] = b.y; gwT[6][d] = b.z; gwT[7][d] = b.w;
    }
    __syncthreads();

    const int lane = tid & 63, wid = tid >> 6;
    const int tbase = (bid * 4 + wid) * 4;          // 4 tokens per wave

    float lg[4][EE];
    #pragma unroll
    for (int t = 0; t < 4; ++t)
      #pragma unroll
      for (int e = 0; e < EE; ++e) lg[t][e] = 0.0f;

    #pragma unroll
    for (int c = 0; c < 4; ++c) {
      const int d = c * 256 + lane * 4;
      float4 gw[EE];
      #pragma unroll
      for (int e = 0; e < EE; ++e)
        gw[e] = *(const float4*)&gwT[e][d];         // ds_read_b128, lanes 16B apart
      #pragma unroll
      for (int t = 0; t < 4; ++t) {
        const size_t off = (size_t)(tbase + t) * DD + d;
        float4 v = *(const float4*)(tokens + off);
        *(ushort4*)(tok_bf + off) =
            make_ushort4(f2bf(v.x), f2bf(v.y), f2bf(v.z), f2bf(v.w));
        #pragma unroll
        for (int e = 0; e < EE; ++e)
          lg[t][e] = fmaf(v.w, gw[e].w, fmaf(v.z, gw[e].z,
                     fmaf(v.y, gw[e].y, fmaf(v.x, gw[e].x, lg[t][e]))));
      }
    }

    // Expert-splitting butterfly reduce, then shuffle softmax/top-2.
    const int b0 = lane & 1, b1 = (lane >> 1) & 1, b2 = (lane >> 2) & 1;
    const int E  = b0 * 4 + (lane & 2) + b2;

    #pragma unroll
    for (int t = 0; t < 4; ++t) {
      float n0[4], n1[2], rr;
      #pragma unroll
      for (int i = 0; i < 4; ++i) {
        float send = b0 ? lg[t][i] : lg[t][i + 4];
        float keep = b0 ? lg[t][i + 4] : lg[t][i];
        n0[i] = keep + __shfl_xor(send, 1, 64);
      }
      #pragma unroll
      for (int i = 0; i < 2; ++i) {
        float send = b1 ? n0[i] : n0[i + 2];
        float keep = b1 ? n0[i + 2] : n0[i];
        n1[i] = keep + __shfl_xor(send, 2, 64);
      }
      {
        float send = b2 ? n1[0] : n1[1];
        float keep = b2 ? n1[1] : n1[0];
        rr = keep + __shfl_xor(send, 4, 64);
      }
      rr += __shfl_xor(rr, 8, 64);
      rr += __shfl_xor(rr, 16, 64);
      rr += __shfl_xor(rr, 32, 64);

      float m = rr;
      m = fmaxf(m, __shfl_xor(m, 1, 64));
      m = fmaxf(m, __shfl_xor(m, 2, 64));
      m = fmaxf(m, __shfl_xor(m, 4, 64));
      float p = __expf(rr - m);
      float s = p;
      s += __shfl_xor(s, 1, 64);
      s += __shfl_xor(s, 2, 64);
      s += __shfl_xor(s, 4, 64);

      int cnt = 0;
      #pragma unroll
      for (int k = 1; k < 8; ++k) {
        float Lo = __shfl_xor(rr, k, 64);
        const int Eo = E ^ ((k & 1) * 4 + (k & 2) + ((k >> 2) & 1));
        cnt += (Lo > rr || (Lo == rr && Eo < E)) ? 1 : 0;
      }
      if (lane < 8) {
        const float w = p / s;
        if (E == 0) scales[(tbase + t) * 2 + 0] = (cnt == 0) ? w : 0.0f;
        if (E == 1) scales[(tbase + t) * 2 + 1] = (cnt == 1) ? w : 0.0f;
      }
      // Active-list build.  E(lane0)=0, E(lane4)=1 by the mapping above.
      const bool myact = (lane == 0 && cnt == 0) || (lane == 4 && cnt == 1);
      const unsigned long long bal = __ballot(myact ? 1 : 0);
      if (bal == 0ULL) {
        // inactive: output row is exactly zero — write it now.
        const size_t ob = (size_t)(tbase + t) * DD;
        const float4 z = make_float4(0.f, 0.f, 0.f, 0.f);
        #pragma unroll
        for (int c = 0; c < 4; ++c)
          *(float4*)(outp + ob + (c * 64 + lane) * 4) = z;
      } else if (lane == 0) {
        const int pos = atomicAdd(counter, 1);
        list[pos] = tbase + t;
      }
    }
  } else {
    const int wb = bid - GATE_BLOCKS;            // 0..2047
    const float* src = (wb < 1024) ? w0 : w1;
    u16*        dst = (wb < 1024) ? w0_bf : w1_bf;
    const int base = (wb & 1023) * 1024 + tid * 4;
    float4 v = *(const float4*)(src + base);
    *(ushort4*)(dst + base) =
        make_ushort4(f2bf(v.x), f2bf(v.y), f2bf(v.z), f2bf(v.w));
  }
}

// ---------------------------------------------------------------------------
// Kernel 2: SPARSE fused dual-GEMM over the active-token list (~23% of rows).
// BM=128 x BN=128, BK=64, 256 threads (4 waves, 2M x 2N, 64x64-dual each).
// Gathered A-staging: global_load_lds source address is PER-LANE, so rows
// come from list[] while the LDS dest stays linear (rule #21 preserved:
// same inverse-swizzled source chunk, same read-side XOR).
// Grid = worst-case 1024 blocks; blocks with m0 >= n_active exit (<1 us).
// One barrier + one vmcnt(0) per tile; r12's SGB interleave pins.
// Epilogue scatters to out[list[m]] with m < n_active guard.
// ---------------------------------------------------------------------------
__global__ __launch_bounds__(256, 1) void moe_gemm_sparse(
    const u16* __restrict__ A,    // [M,K] bf16 (token-major)
    const u16* __restrict__ Bw0,  // [N,K] bf16
    const u16* __restrict__ Bw1,  // [N,K] bf16
    const float* __restrict__ bias0, const float* __restrict__ bias1,
    const float* __restrict__ scales, // [M,2]
    const int* __restrict__ list, const int* __restrict__ counter,
    float* __restrict__ out)      // [M,N] f32
{
  const int n_active = *counter;
  const int bid = blockIdx.x;
  const int bm = bid >> 3, bn = bid & 7;
  const int m0 = bm * 128, n0 = bn * 128;
  if (m0 >= n_active) return;

  __shared__ u16 lA [2][128 * BK];   // 32 KiB
  __shared__ u16 lB0[2][128 * BK];   // 32 KiB
  __shared__ u16 lB1[2][128 * BK];   // 32 KiB -> 96 KiB

  const int tid = threadIdx.x;
  const int lane = tid & 63;
  const int wid  = tid >> 6;                  // 0..3
  const int wm = wid >> 1, wn = wid & 1;      // 2M x 2N wave grid
  const int fr = lane & 15, fq = lane >> 4;
  const int frh = fr >> 1;                    // read-swizzle term

  // staging: thread covers rows {tid>>3 + 32c}, phys chunk tid&7.
  // (row>>1)&7 == (tid>>4)&7 for all c (32c contributes multiples of 16).
  const int schunk = ((tid & 7) ^ ((tid >> 4) & 7)) * 8;
  const u16* gAr[4];
  #pragma unroll
  for (int c = 0; c < 4; ++c) {
    int m = m0 + (tid >> 3) + 32 * c;
    if (m >= n_active) m = n_active - 1;      // pad: duplicate last row
    gAr[c] = A + (size_t)list[m] * K_TOT + schunk;
  }
  const u16* gB0 = Bw0 + (size_t)(n0 + (tid >> 3)) * K_TOT + schunk;
  const u16* gB1 = Bw1 + (size_t)(n0 + (tid >> 3)) * K_TOT + schunk;

#define STAGE_A(buf, c, ko)  stage16(&lA [buf][(c)*2048 + tid*8], gAr[c] + (ko))
#define STAGE_B0(buf, c, ko) stage16(&lB0[buf][(c)*2048 + tid*8], gB0 + (size_t)(c)*32*K_TOT + (ko))
#define STAGE_B1(buf, c, ko) stage16(&lB1[buf][(c)*2048 + tid*8], gB1 + (size_t)(c)*32*K_TOT + (ko))

#define FRAG(L, buf, rowbase, kk) \
  (*(const bf16x8*)&L[buf][((rowbase) + fr) * BK + ((((kk) << 2) | fq) ^ frh) * 8])

#define BAR()        __builtin_amdgcn_s_barrier()
#define WAIT_VM(N)   asm volatile("s_waitcnt vmcnt(" #N ")" ::: "memory")
#define SGB(m, n)    __builtin_amdgcn_sched_group_barrier((m), (n), 0)

#define MFMA16(ACC, AF, BF) do {                                              \
    __builtin_amdgcn_s_setprio(1);                                            \
    _Pragma("unroll")                                                         \
    for (int i = 0; i < 4; ++i)                                               \
      _Pragma("unroll")                                                       \
      for (int j = 0; j < 4; ++j)                                             \
        ACC[i][j] = __builtin_amdgcn_mfma_f32_16x16x32_bf16(AF[i], BF[j],     \
                                                            ACC[i][j], 0,0,0);\
    __builtin_amdgcn_s_setprio(0);                                            \
  } while (0)

#define STAGE_ALL(buf, ko) do {                                               \
    STAGE_A(buf, 0, ko);  STAGE_A(buf, 1, ko);                                \
    STAGE_A(buf, 2, ko);  STAGE_A(buf, 3, ko);                                \
    STAGE_B0(buf, 0, ko); STAGE_B0(buf, 1, ko);                               \
    STAGE_B0(buf, 2, ko); STAGE_B0(buf, 3, ko);                               \
    STAGE_B1(buf, 0, ko); STAGE_B1(buf, 1, ko);                               \
    STAGE_B1(buf, 2, ko); STAGE_B1(buf, 3, ko);                               \
  } while (0)

  f32x4 acc0[4][4] = {};
  f32x4 acc1[4][4] = {};
  bf16x8 afA[4], afB[4], b0A[4], b0B[4], b1A[4], b1B[4];

  // Prologue: stage K-tile 0, drain, barrier.
  STAGE_ALL(0, 0);
  WAIT_VM(0);
  BAR();

  int cur = 0;
  for (int t = 0; t < NT - 1; ++t) {
    const int nxt = cur ^ 1;
    const size_t ko = (size_t)(t + 1) * BK;

    // reads: q1(afA,b0A) q2(afB,b0B) q3(b1A,b1B)
    #pragma unroll
    for (int i = 0; i < 4; ++i) afA[i] = FRAG(lA,  cur, wm * 64 + i * 16, 0);
    #pragma unroll
    for (int j = 0; j < 4; ++j) b0A[j] = FRAG(lB0, cur, wn * 64 + j * 16, 0);
    #pragma unroll
    for (int i = 0; i < 4; ++i) afB[i] = FRAG(lA,  cur, wm * 64 + i * 16, 1);
    #pragma unroll
    for (int j = 0; j < 4; ++j) b0B[j] = FRAG(lB0, cur, wn * 64 + j * 16, 1);
    #pragma unroll
    for (int j = 0; j < 4; ++j) b1A[j] = FRAG(lB1, cur, wn * 64 + j * 16, 0);
    #pragma unroll
    for (int j = 0; j < 4; ++j) b1B[j] = FRAG(lB1, cur, wn * 64 + j * 16, 1);
    STAGE_ALL(nxt, ko);

    MFMA16(acc0, afA, b0A);
    MFMA16(acc0, afB, b0B);
    MFMA16(acc1, afA, b1A);
    MFMA16(acc1, afB, b1B);

    // interleave pins: batch1 after q1; stages+q2/q3 drain under batches.
    SGB(0x100, 8);  SGB(0x008, 16);
    SGB(0x100, 8);  SGB(0x010, 4);  SGB(0x008, 16);
    SGB(0x100, 8);  SGB(0x010, 8);  SGB(0x008, 16);
    SGB(0x008, 16);

    WAIT_VM(0);
    BAR();
    cur = nxt;
  }

  // Peeled last tile (no prefetch).
  {
    #pragma unroll
    for (int i = 0; i < 4; ++i) afA[i] = FRAG(lA,  cur, wm * 64 + i * 16, 0);
    #pragma unroll
    for (int j = 0; j < 4; ++j) b0A[j] = FRAG(lB0, cur, wn * 64 + j * 16, 0);
    #pragma unroll
    for (int i = 0; i < 4; ++i) afB[i] = FRAG(lA,  cur, wm * 64 + i * 16, 1);
    #pragma unroll
    for (int j = 0; j < 4; ++j) b0B[j] = FRAG(lB0, cur, wn * 64 + j * 16, 1);
    #pragma unroll
    for (int j = 0; j < 4; ++j) b1A[j] = FRAG(lB1, cur, wn * 64 + j * 16, 0);
    #pragma unroll
    for (int j = 0; j < 4; ++j) b1B[j] = FRAG(lB1, cur, wn * 64 + j * 16, 1);
    MFMA16(acc0, afA, b0A);
    MFMA16(acc0, afB, b0B);
    MFMA16(acc1, afA, b1A);
    MFMA16(acc1, afB, b1B);
  }

  // Epilogue: scatter out[list[m]] = s0*silu(acc0+b0) + s1*silu(acc1+b1)
  float bb0[4], bb1[4];
  #pragma unroll
  for (int j = 0; j < 4; ++j) {
    const int col = n0 + wn * 64 + j * 16 + fr;
    bb0[j] = bias0[col];
    bb1[j] = bias1[col];
  }
  #pragma unroll
  for (int i = 0; i < 4; ++i) {
    #pragma unroll
    for (int r = 0; r < 4; ++r) {
      const int m = m0 + wm * 64 + i * 16 + fq * 4 + r;  // C row=(lane>>4)*4+reg
      if (m < n_active) {
        const int gidx = list[m];
        const float s0 = scales[gidx * 2 + 0];
        const float s1 = scales[gidx * 2 + 1];
        float* orow = out + (size_t)gidx * N_TOT + n0 + wn * 64;
        #pragma unroll
        for (int j = 0; j < 4; ++j) {
          const float v0 = acc0[i][j][r] + bb0[j];
          const float v1 = acc1[i][j][r] + bb1[j];
          const float g0 = v0 / (1.0f + __expf(-v0));
          const float g1 = v1 / (1.0f + __expf(-v1));
          orow[j * 16 + fr] = s0 * g0 + s1 * g1;           // col = lane&15
        }
      }
    }
  }
#undef STAGE_A
#undef STAGE_B0
#undef STAGE_B1
#undef STAGE_ALL
#undef FRAG
#undef BAR
#undef WAIT_VM
#undef SGB
#undef MFMA16
}

// ---------------------------------------------------------------------------
extern "C" void kernel_launch(void* const* d_in, const int* in_sizes, int n_in,
                              void* d_out, int out_size, void* d_ws, size_t ws_size,
                              hipStream_t stream)
{
  const float* tokens = (const float*)d_in[0];
  const float* gate_w = (const float*)d_in[1];
  const float* w0     = (const float*)d_in[2];
  const float* b0     = (const float*)d_in[3];
  const float* w1     = (const float*)d_in[4];
  const float* b1     = (const float*)d_in[5];
  float* out = (float*)d_out;

  char* ws = (char*)d_ws;
  const size_t off_w0  = (size_t)M_TOT * K_TOT * 2;            // 32 MB
  const size_t off_w1  = off_w0 + (size_t)N_TOT * K_TOT * 2;   // +2 MB
  const size_t off_sc  = off_w1 + (size_t)N_TOT * K_TOT * 2;   // +2 MB
  const size_t off_cnt = off_sc + (size_t)M_TOT * 2 * 4;       // +128 KB
  const size_t off_lst = off_cnt + 256;

  u16* tok_bf   = (u16*)ws;
  u16* w0_bf    = (u16*)(ws + off_w0);
  u16* w1_bf    = (u16*)(ws + off_w1);
  float* scales = (float*)(ws + off_sc);
  int* counter  = (int*)(ws + off_cnt);
  int* list     = (int*)(ws + off_lst);

  hipMemsetAsync(counter, 0, sizeof(int), stream);

  gate_convert_kernel<<<GATE_BLOCKS + 2048, 256, 0, stream>>>(
      tokens, gate_w, w0, w1, tok_bf, w0_bf, w1_bf, scales, counter, list, out);

  moe_gemm_sparse<<<(M_TOT / 128) * (N_TOT / 128), 256, 0, stream>>>(
      tok_bf, w0_bf, w1_bf, b0, b1, scales, list, counter, out);
}